// Round 6
// baseline (3579.168 us; speedup 1.0000x reference)
//
#include <hip/hip_runtime.h>
#include <hip/hip_bf16.h>

typedef __bf16 bf16x8 __attribute__((ext_vector_type(8)));
typedef float f32x4 __attribute__((ext_vector_type(4)));
typedef float f32x16 __attribute__((ext_vector_type(16)));
typedef unsigned int u32x4 __attribute__((ext_vector_type(4)));
typedef unsigned int u32x2 __attribute__((ext_vector_type(2)));

#define BB   128
#define SS   512
#define DD   128
#define HH   1024
#define OO   64
#define IIN  257

// 4 batch groups (32 rows) x 64 blocks; block owns 16 h-cols (64 gate cols,
// packed n = cl*4 + gate). 2 waves/block: wave = n-tile of 32 gate cols.
// MFMA 32x32x16: one M-tile = whole group batch.
#define NGROUP 4
#define GBLK   64
#define MG     32
#define KKX    18                 // x-part ksteps (K=288 = 18*16)
#define KKH    64                 // h-part ksteps (K=1024 = 64*16)

#define XTP_TP    (KKX*512)       // 9216 bf16 per (t,p)
#define HBUF_SLAB (KKH*512)       // 32768 bf16 = 64 KB per (p,buf)
#define WIH_BLK   (2*KKX*512)     // 18432 bf16 = 36 KB per q

#define WS_HBUF  1024
#define WS_HLAST 525312
#define WS_XTP   1049600
#define WS_WIHP  38798336

// ---- device-scope (sc1) ops: bypass L1/L2, coherent at L3 (MALL). No
// buffer_wbl2/buffer_inv anywhere -> no cache-maintenance serialization.
__device__ __forceinline__ u32x4 ldg_dev16(const void* p) {
  u32x4 r;
  asm volatile("global_load_dwordx4 %0, %1, off sc1" : "=v"(r) : "v"(p));
  return r;
}
__device__ __forceinline__ void stg_dev4(void* p, unsigned int v) {
  asm volatile("global_store_dword %0, %1, off sc1" :: "v"(p), "v"(v));
}
__device__ __forceinline__ void stg_dev8(void* p, u32x2 v) {
  asm volatile("global_store_dwordx2 %0, %1, off sc1" :: "v"(p), "v"(v));
}
__device__ __forceinline__ bf16x8 asbf(u32x4 v) {
  union { u32x4 u; bf16x8 h; } c; c.u = v; return c.h;
}

#define CLAIMW(CNTSTR, A)                                            \
  asm volatile("s_waitcnt vmcnt(" CNTSTR ")"                         \
    : "+v"((A)[0]), "+v"((A)[1]), "+v"((A)[2]), "+v"((A)[3]),        \
      "+v"((A)[4]), "+v"((A)[5]), "+v"((A)[6]), "+v"((A)[7]))

// xtp A-frags (32x32x16 A layout: m=lane&31, k=kk*16+(lane>>5)*8+j):
// idx = ((t*4+p)*18 + kk)*512 + l*8 + j
__global__ void prepack_kernel(const float* __restrict__ x, const float* __restrict__ mask,
                               const float* __restrict__ ti, __bf16* __restrict__ xtp) {
  int idx = blockIdx.x * 256 + threadIdx.x;        // 18,874,368
  int j = idx & 7, l = (idx >> 3) & 63;
  int rest = idx >> 9;
  int kk = rest % KKX;
  int rest2 = rest / KKX;
  int p = rest2 & 3, t = rest2 >> 2;
  int b = p * MG + (l & 31);
  int k = kk * 16 + ((l >> 5) << 3) + j;
  float v;
  if (k < 128)       v = x[(b * SS + t) * DD + k];
  else if (k < 256)  v = mask[(b * SS + t) * DD + (k - 128)];
  else if (k == 256) v = ti[b * SS + t];
  else               v = 0.f;
  xtp[idx] = (__bf16)v;
}

// W_ih B-frags per col-slice q, gate-quad packed: n = cl*4 + gate.
// idx = ((q*2+nt)*18 + kk)*512 + l*8 + j
__global__ void wih_prepack(const float* __restrict__ W_ih, __bf16* __restrict__ wihp) {
  int idx = blockIdx.x * 256 + threadIdx.x;        // 1,179,648
  int j = idx & 7, l = (idx >> 3) & 63;
  int rest = idx >> 9;
  int kk = rest % KKX;
  int rest2 = rest / KKX;
  int nt = rest2 & 1, q = rest2 >> 1;
  int n = nt * 32 + (l & 31);
  int g = n & 3, cl = n >> 2;
  int col = g * HH + q * 16 + cl;
  int k = kk * 16 + ((l >> 5) << 3) + j;
  wihp[idx] = (k < IIN) ? (__bf16)W_ih[col * IIN + k] : (__bf16)0.f;
}

__device__ __forceinline__ float sigmoid_f(float v) { return 1.f / (1.f + __expf(-v)); }
__device__ __forceinline__ float tanh_f(float v)    { return 1.f - 2.f / (__expf(2.f * v) + 1.f); }

// one 8-kstep h chunk: claim loads, 8 MFMAs, optionally prefetch next chunk
#define HCHUNK8(AARR, KB, PREFB, DOPREF, CNTSTR) do {                          \
    CLAIMW(CNTSTR, AARR);                                                      \
    _Pragma("unroll")                                                          \
    for (int i_ = 0; i_ < 8; ++i_) {                                           \
      bf16x8 b_ = *(const bf16x8*)(whh_lds + (nt * KKH + (KB) + i_) * 512 + l * 8); \
      acc = __builtin_amdgcn_mfma_f32_32x32x16_bf16(asbf(AARR[i_]), b_, acc, 0, 0, 0); \
    }                                                                          \
    if (DOPREF) {                                                              \
      _Pragma("unroll")                                                        \
      for (int i_ = 0; i_ < 8; ++i_) AARR[i_] = ldg_dev16(hbL + ((PREFB) + i_) * 512); \
    }                                                                          \
  } while (0)

__launch_bounds__(128, 1)
__global__ void lstm_scan(const float* __restrict__ W_hh,
                          const float* __restrict__ b_ih, const float* __restrict__ b_hh,
                          const __bf16* __restrict__ xtp, const __bf16* __restrict__ wihp,
                          __bf16* __restrict__ hbuf,
                          float* __restrict__ hlast, unsigned int* __restrict__ flags) {
  __shared__ __bf16 whh_lds[2 * KKH * 512];   // 128 KB: [nt][kk][lane][j]
  __shared__ float  gstage[32 * 64];          // 8 KB: [row][n], n = cl*4+gate

  const int tid = threadIdx.x;
  const int bid = blockIdx.x;
  // group p -> XCD pair {2p, 2p+1}; q = col-slice within group
  const int p = (bid & 7) >> 1;
  const int q = (bid >> 3) * 2 + (bid & 1);    // [0,64)
  const int j0 = q * 16;                       // owned h-cols [j0, j0+16)

  // ---- one-time: pack W_hh slice in 32x32x16 B-frag order, gate-quad cols ----
  for (int e = tid; e < 2 * KKH * 512; e += 128) {
    int j = e & 7, l = (e >> 3) & 63, kk = (e >> 9) & 63, nt = e >> 15;
    int n = nt * 32 + (l & 31);
    int g = n & 3, cl = n >> 2;
    int k = kk * 16 + ((l >> 5) << 3) + j;
    whh_lds[e] = (__bf16)W_hh[(g * HH + j0 + cl) * HH + k];
  }
  __syncthreads();

  const int w = tid >> 6, l = tid & 63;
  const int nt = w;                            // wave = n-tile
  unsigned int* gflags = flags + p * 64;

  // per-lane bias for its C-column n (added at gstage write)
  const int n_own = nt * 32 + (l & 31);
  const int g_own = n_own & 3, cl_own = n_own >> 2;
  const float bias_n = b_ih[g_own * HH + j0 + cl_own] + b_hh[g_own * HH + j0 + cl_own];

  // gate-phase cell ownership: (row = tid>>2, cols j0 + (tid&3)*4 + s)
  const int grow = tid >> 2, gcl0 = (tid & 3) * 4;
  float creg[4] = {0.f, 0.f, 0.f, 0.f};

  const __bf16* wpn = wihp + ((size_t)q * 2 + nt) * (KKX * 512) + l * 8;

  // x-part(0) into acc
  f32x16 acc;
  {
    f32x16 z = {0.f}; acc = z;
    const __bf16* xb = xtp + ((size_t)(0 * 4 + p) * KKX) * 512 + l * 8;
    #pragma unroll
    for (int kk = 0; kk < KKX; ++kk) {
      bf16x8 a = *(const bf16x8*)(xb + kk * 512);
      bf16x8 b = *(const bf16x8*)(wpn + kk * 512);
      acc = __builtin_amdgcn_mfma_f32_32x32x16_bf16(a, b, acc, 0, 0, 0);
    }
  }

  for (int t = 0; t < SS; ++t) {
    const int rb = t & 1, wb = rb ^ 1;

    // ---- barrier wait: all 64 group blocks published h_t (sc1 polls) ----
    if (t > 0) {
      if (tid < 64) {
        const unsigned int tgt = (unsigned int)t;
        for (;;) {
          unsigned int fa;
          asm volatile("global_load_dword %0, %1, off sc1\n\t"
                       "s_waitcnt vmcnt(0)"
                       : "=v"(fa) : "v"(gflags + tid));
          if (!__ballot(fa < tgt)) break;
          __builtin_amdgcn_s_sleep(1);
        }
      }
      __syncthreads();
    }

    // issue h A chunks 0,1 (sc1 from L3)
    const __bf16* hbL = hbuf + (p * 2 + rb) * HBUF_SLAB + l * 8;
    u32x4 A0[8], A1[8];
    #pragma unroll
    for (int i = 0; i < 8; ++i) A0[i] = ldg_dev16(hbL + i * 512);
    #pragma unroll
    for (int i = 0; i < 8; ++i) A1[i] = ldg_dev16(hbL + (8 + i) * 512);

    // x-part(t+1) into xacc while h loads fly (vmcnt FIFO: x waits imply
    // h chunks 0,1 resident by the time we claim them)
    f32x16 xacc;
    {
      f32x16 z = {0.f}; xacc = z;
      int tn = (t + 1 < SS) ? t + 1 : SS - 1;
      const __bf16* xb = xtp + ((size_t)(tn * 4 + p) * KKX) * 512 + l * 8;
      #pragma unroll
      for (int kk = 0; kk < KKX; ++kk) {
        bf16x8 a = *(const bf16x8*)(xb + kk * 512);
        bf16x8 b = *(const bf16x8*)(wpn + kk * 512);
        xacc = __builtin_amdgcn_mfma_f32_32x32x16_bf16(a, b, xacc, 0, 0, 0);
      }
    }

    // h-part: 64 ksteps, 8 chunks, depth-16 prefetch, partial vmcnt claims
    HCHUNK8(A0,  0, 16, 1, "8");
    HCHUNK8(A1,  8, 24, 1, "8");
    HCHUNK8(A0, 16, 32, 1, "8");
    HCHUNK8(A1, 24, 40, 1, "8");
    HCHUNK8(A0, 32, 48, 1, "8");
    HCHUNK8(A1, 40, 56, 1, "8");
    HCHUNK8(A0, 48,  0, 0, "8");
    HCHUNK8(A1, 56,  0, 0, "0");

    // stage gates + bias to LDS: [row][n], C layout row=(r&3)+8*(r>>2)+4*(l>>5)
    #pragma unroll
    for (int r = 0; r < 16; ++r) {
      int row = (r & 3) + 8 * (r >> 2) + 4 * (l >> 5);
      gstage[row * 64 + n_own] = acc[r] + bias_n;
    }
    __syncthreads();

    // gate phase: 128 threads x 4 cells (row, j0+gcl0+s); h -> one dwordx2
    {
      __bf16* hw = hbuf + (p * 2 + wb) * HBUF_SLAB;
      float h4[4];
      #pragma unroll
      for (int s = 0; s < 4; ++s) {
        f32x4 g4 = *(const f32x4*)(gstage + grow * 64 + (gcl0 + s) * 4);
        float i_ = sigmoid_f(g4[0]);
        float f_ = sigmoid_f(g4[1]);
        float gg = tanh_f(g4[2]);
        float o_ = sigmoid_f(g4[3]);
        float c  = f_ * creg[s] + i_ * gg;
        creg[s] = c;
        h4[s] = o_ * tanh_f(c);
      }
      union { __bf16 h[4]; u32x2 u; } pk;
      #pragma unroll
      for (int s = 0; s < 4; ++s) pk.h[s] = (__bf16)h4[s];
      int el = q * 512 + ((gcl0 >> 3) * 32 + grow) * 8 + (gcl0 & 7);
      stg_dev8(hw + el, pk.u);
      if (t == SS - 1) {
        f32x4 hv = {h4[0], h4[1], h4[2], h4[3]};
        *(f32x4*)(hlast + (p * MG + grow) * HH + j0 + gcl0) = hv;
      }
    }

    // ---- signal: drain h stores to L3, then release own flag ----
    asm volatile("s_waitcnt vmcnt(0)" ::: "memory");
    __syncthreads();
    if (t < SS - 1 && tid == 0) {
      stg_dev4(gflags + q, (unsigned int)(t + 1));
    }

    acc = xacc;   // carry x(t+1)
  }
}

__global__ void fc_kernel(const float* __restrict__ hlast, const float* __restrict__ W_fc,
                          const float* __restrict__ b_fc, float* __restrict__ out) {
  int b = blockIdx.x;            // 128
  int t = threadIdx.x;           // 256
  int o = t >> 2, part = t & 3;
  const float* hr = hlast + b * HH;
  const float* wr = W_fc + o * HH;
  float s = 0.f;
  #pragma unroll 4
  for (int k0 = part * 4; k0 < HH; k0 += 16) {
    float4 hv = *(const float4*)(hr + k0);
    float4 wv = *(const float4*)(wr + k0);
    s += hv.x * wv.x + hv.y * wv.y + hv.z * wv.z + hv.w * wv.w;
  }
  s += __shfl_xor(s, 1);
  s += __shfl_xor(s, 2);
  if (part == 0) out[b * OO + o] = s + b_fc[o];
}

extern "C" void kernel_launch(void* const* d_in, const int* in_sizes, int n_in,
                              void* d_out, int out_size, void* d_ws, size_t ws_size,
                              hipStream_t stream) {
  const float* x    = (const float*)d_in[0];
  const float* mask = (const float*)d_in[1];
  const float* ti   = (const float*)d_in[2];
  const float* W_ih = (const float*)d_in[3];
  const float* W_hh = (const float*)d_in[4];
  const float* b_ih = (const float*)d_in[5];
  const float* b_hh = (const float*)d_in[6];
  const float* W_fc = (const float*)d_in[7];
  const float* b_fc = (const float*)d_in[8];
  float* out = (float*)d_out;

  char* ws = (char*)d_ws;
  unsigned int* flags = (unsigned int*)ws;
  __bf16* hbuf  = (__bf16*)(ws + WS_HBUF);
  float*  hlast = (float*)(ws + WS_HLAST);
  __bf16* xtp   = (__bf16*)(ws + WS_XTP);
  __bf16* wihp  = (__bf16*)(ws + WS_WIHP);

  // zero flags + h double-buffers (ws poisoned 0xAA before each launch)
  hipMemsetAsync(ws, 0, WS_HLAST, stream);

  prepack_kernel<<<(SS * NGROUP * XTP_TP) / 256, 256, 0, stream>>>(x, mask, ti, xtp);
  wih_prepack<<<(GBLK * WIH_BLK) / 256, 256, 0, stream>>>(W_ih, wihp);
  lstm_scan<<<NGROUP * GBLK, 128, 0, stream>>>(W_hh, b_ih, b_hh, xtp, wihp, hbuf, hlast, flags);
  fc_kernel<<<BB, 256, 0, stream>>>(hlast, W_fc, b_fc, out);
}

// Round 7
// 2245.467 us; speedup vs baseline: 1.5940x; 1.5940x over previous
//
#include <hip/hip_runtime.h>
#include <hip/hip_bf16.h>

typedef __bf16 bf16x8 __attribute__((ext_vector_type(8)));
typedef float f32x4 __attribute__((ext_vector_type(4)));
typedef float f32x2 __attribute__((ext_vector_type(2)));
typedef unsigned int u32x4 __attribute__((ext_vector_type(4)));

#define BB   128
#define SS   512
#define DD   128
#define HH   1024
#define OO   64
#define IIN  257

// 4 batch groups (32 rows) x 64 blocks; block owns 16 h-cols (64 gate cols =
// 4 gates x 16). 4 waves = 4 K-quarters. W_hh B-fragments persistent in VGPRs.
#define NGROUP 4
#define GBLK   64
#define MG     32
#define KK_H   32     // 1024/32 ksteps (16x16x32)
#define KK_X   9      // 288/32

#define XTP_MT    (KK_X*512)      // 4608 bf16 per (t,p,mt)
#define HBUF_SLAB (2*KK_H*512)    // 32768 bf16 = 64 KB per (p,buf)
#define WIH_BLK   (4*KK_X*512)    // 18432 bf16 per q
#define RS        132             // padded row-kq stride (floats) per (g,cl)

#define WS_HBUF  1024
#define WS_HLAST 525312
#define WS_XTP   1049600
#define WS_WIHP  38798336

// ---- device-scope (sc1) ops: bypass L1/L2, coherent at L3 (MALL). No
// buffer_wbl2/buffer_inv anywhere -> no cache-maintenance serialization.
__device__ __forceinline__ u32x4 ldg_dev16(const void* p) {
  u32x4 r;
  asm volatile("global_load_dwordx4 %0, %1, off sc1" : "=v"(r) : "v"(p));
  return r;
}
__device__ __forceinline__ void stg_dev4(void* p, unsigned int v) {
  asm volatile("global_store_dword %0, %1, off sc1" :: "v"(p), "v"(v));
}
__device__ __forceinline__ bf16x8 asbf(u32x4 v) {
  union { u32x4 u; bf16x8 h; } c; c.u = v; return c.h;
}

#define CLAIMW(CNTSTR, A)                                            \
  asm volatile("s_waitcnt vmcnt(" CNTSTR ")"                         \
    : "+v"((A)[0]), "+v"((A)[1]), "+v"((A)[2]), "+v"((A)[3]),        \
      "+v"((A)[4]), "+v"((A)[5]), "+v"((A)[6]), "+v"((A)[7]))

// xtp A-frags (16x16x32 A: m=lane&15, k=kk*32+(lane>>4)*8+j):
// idx = (((t*4+p)*2+mt)*9 + kk)*512 + l*8 + j
__global__ void prepack_kernel(const float* __restrict__ x, const float* __restrict__ mask,
                               const float* __restrict__ ti, __bf16* __restrict__ xtp) {
  int idx = blockIdx.x * 256 + threadIdx.x;        // 18,874,368
  int j = idx & 7, l = (idx >> 3) & 63;
  int rest = idx >> 9;
  int kk = rest % 9;
  int rest2 = rest / 9;
  int mt = rest2 & 1;
  int rest3 = rest2 >> 1;
  int p = rest3 & 3;
  int t = rest3 >> 2;
  int b = p * MG + mt * 16 + (l & 15);
  int k = kk * 32 + ((l >> 4) << 3) + j;
  float v;
  if (k < 128)       v = x[(b * SS + t) * DD + k];
  else if (k < 256)  v = mask[(b * SS + t) * DD + (k - 128)];
  else if (k == 256) v = ti[b * SS + t];
  else               v = 0.f;
  xtp[idx] = (__bf16)v;
}

// W_ih B-frags per col-slice q: [q][nt][kk][lane][8], nt = gate
__global__ void wih_prepack(const float* __restrict__ W_ih, __bf16* __restrict__ wihp) {
  int idx = blockIdx.x * 256 + threadIdx.x;        // 1,179,648
  int j = idx & 7, l = (idx >> 3) & 63;
  int rest = idx >> 9;
  int kk = rest % 9;
  int rest2 = rest / 9;
  int nt = rest2 & 3, q = rest2 >> 2;
  int col = nt * HH + q * 16 + (l & 15);
  int k = kk * 32 + ((l >> 4) << 3) + j;
  wihp[idx] = (k < IIN) ? (__bf16)W_ih[col * IIN + k] : (__bf16)0.f;
}

__device__ __forceinline__ float sigmoid_f(float v) { return 1.f / (1.f + __expf(-v)); }
__device__ __forceinline__ float tanh_f(float v)    { return 1.f - 2.f / (__expf(2.f * v) + 1.f); }

__launch_bounds__(256, 1)
__global__ void lstm_scan(const float* __restrict__ W_hh,
                          const float* __restrict__ b_ih, const float* __restrict__ b_hh,
                          const __bf16* __restrict__ xtp, const __bf16* __restrict__ wihp,
                          __bf16* __restrict__ hbuf,
                          float* __restrict__ hlast, unsigned int* __restrict__ flags) {
  __shared__ float red_lds[4 * 16 * RS];      // 33 KB: [g][cl] x (row*4 + kq), padded

  const int tid = threadIdx.x;
  const int bid = blockIdx.x;
  // group p -> XCD pair {2p,2p+1}; q = col slice within group
  const int p = (bid & 7) >> 1;
  const int q = (bid >> 3) * 2 + (bid & 1);    // [0,64)
  const int j0 = q * 16;                       // owned h-cols [j0, j0+16)

  const int w = tid >> 6, l = tid & 63;        // wave = K-quarter
  const int n16 = l & 15, qh = l >> 4;
  unsigned int* gflags = flags + p * 64;

  // ---- W_hh B-fragments persistent in VGPRs: [nt][i], kk = w*8+i ----
  // B-frag (16x16x32): n = n16, k = kk*32 + qh*8 + j  (8 contiguous k)
  bf16x8 breg[4][8];
  #pragma unroll
  for (int ntI = 0; ntI < 4; ++ntI) {
    const float* wrow = W_hh + (size_t)(ntI * HH + j0 + n16) * HH;
    #pragma unroll
    for (int i = 0; i < 8; ++i) {
      const float* src = wrow + (w * 8 + i) * 32 + qh * 8;
      bf16x8 bv;
      #pragma unroll
      for (int jj = 0; jj < 8; ++jj) bv[jj] = (__bf16)src[jj];
      breg[ntI][i] = bv;
    }
  }

  // gate-phase ownership: thread = (m = tid>>3, clp = tid&7) -> cells (m, clp*2+s)
  const int gm = tid >> 3, clp = tid & 7;
  float bias_r[4][2];
  #pragma unroll
  for (int g = 0; g < 4; ++g)
    #pragma unroll
    for (int s = 0; s < 2; ++s) {
      int col = g * HH + j0 + clp * 2 + s;
      bias_r[g][s] = b_ih[col] + b_hh[col];
    }
  float creg[2] = {0.f, 0.f};

  // x-part K split over waves: kk in [xs, xe)
  const int xs = (w == 0) ? 0 : (2 * w + 1);
  const int xe = xs + ((w == 0) ? 3 : 2);

  for (int t = 0; t < SS; ++t) {
    const int rb = t & 1, wb = rb ^ 1;
    f32x4 acc[2][4];
    #pragma unroll
    for (int mt = 0; mt < 2; ++mt)
      #pragma unroll
      for (int ntI = 0; ntI < 4; ++ntI) acc[mt][ntI] = (f32x4){0.f, 0.f, 0.f, 0.f};

    // x-part (this wave's K-slice), pre-poll; A from xtp, B from wihp (L2-cached)
    for (int kk = xs; kk < xe; ++kk) {
      #pragma unroll
      for (int mt = 0; mt < 2; ++mt) {
        const __bf16* xb = xtp + ((size_t)((t * 4 + p) * 2 + mt)) * XTP_MT + kk * 512 + l * 8;
        bf16x8 a = *(const bf16x8*)xb;
        #pragma unroll
        for (int ntI = 0; ntI < 4; ++ntI) {
          bf16x8 b = *(const bf16x8*)(wihp + ((size_t)(q * 4 + ntI) * 9 + kk) * 512 + l * 8);
          acc[mt][ntI] = __builtin_amdgcn_mfma_f32_16x16x32_bf16(a, b, acc[mt][ntI], 0, 0, 0);
        }
      }
    }

    // ---- barrier wait: all 64 group blocks published h_t (sc1 polls) ----
    if (t > 0) {
      if (tid < 64) {
        const unsigned int tgt = (unsigned int)t;
        for (;;) {
          unsigned int fa;
          asm volatile("global_load_dword %0, %1, off sc1\n\t"
                       "s_waitcnt vmcnt(0)"
                       : "=v"(fa) : "v"(gflags + tid));
          if (!__ballot(fa < tgt)) break;
          __builtin_amdgcn_s_sleep(1);
        }
      }
      __syncthreads();
    }

    // h-part: this wave's K-quarter (8 ksteps) x 2 m-tiles. A via sc1 from L3,
    // B from persistent VGPRs (zero LDS reads).
    {
      const __bf16* hbL = hbuf + (p * 2 + rb) * HBUF_SLAB + l * 8;
      u32x4 A0[8], A1[8];
      #pragma unroll
      for (int i = 0; i < 8; ++i) A0[i] = ldg_dev16(hbL + (w * 8 + i) * 512);
      #pragma unroll
      for (int i = 0; i < 8; ++i) A1[i] = ldg_dev16(hbL + (32 + w * 8 + i) * 512);

      CLAIMW("8", A0);
      #pragma unroll
      for (int i = 0; i < 8; ++i)
        #pragma unroll
        for (int ntI = 0; ntI < 4; ++ntI)
          acc[0][ntI] = __builtin_amdgcn_mfma_f32_16x16x32_bf16(asbf(A0[i]), breg[ntI][i], acc[0][ntI], 0, 0, 0);

      CLAIMW("0", A1);
      #pragma unroll
      for (int i = 0; i < 8; ++i)
        #pragma unroll
        for (int ntI = 0; ntI < 4; ++ntI)
          acc[1][ntI] = __builtin_amdgcn_mfma_f32_16x16x32_bf16(asbf(A1[i]), breg[ntI][i], acc[1][ntI], 0, 0, 0);
    }

    // ---- deposit K-partials: red[(g*16+cl)*RS + row*4 + kq] ----
    #pragma unroll
    for (int mt = 0; mt < 2; ++mt)
      #pragma unroll
      for (int ntI = 0; ntI < 4; ++ntI)
        #pragma unroll
        for (int r = 0; r < 4; ++r)
          red_lds[(ntI * 16 + n16) * RS + (mt * 16 + qh * 4 + r) * 4 + w] = acc[mt][ntI][r];
    __syncthreads();

    // ---- gate phase: sum 4 K-partials (f32x4 read), LSTM cell, store h ----
    {
      __bf16* hw = hbuf + (p * 2 + wb) * HBUF_SLAB;
      float h2[2];
      #pragma unroll
      for (int s = 0; s < 2; ++s) {
        int cl = clp * 2 + s;
        float gv[4];
        #pragma unroll
        for (int g = 0; g < 4; ++g) {
          f32x4 v = *(const f32x4*)(red_lds + (g * 16 + cl) * RS + gm * 4);
          gv[g] = (v[0] + v[1]) + (v[2] + v[3]) + bias_r[g][s];
        }
        float i_ = sigmoid_f(gv[0]);
        float f_ = sigmoid_f(gv[1]);
        float g_ = tanh_f(gv[2]);
        float o_ = sigmoid_f(gv[3]);
        float c  = f_ * creg[s] + i_ * g_;
        creg[s] = c;
        h2[s] = o_ * tanh_f(c);
      }
      union { __bf16 h[2]; unsigned int u; } pk;
      pk.h[0] = (__bf16)h2[0];
      pk.h[1] = (__bf16)h2[1];
      int k = j0 + clp * 2;
      int mt2 = gm >> 4, mm = gm & 15, kk2 = k >> 5, q2 = (k >> 3) & 3, jj = k & 7;
      stg_dev4(hw + ((mt2 * 32 + kk2) * 64 + q2 * 16 + mm) * 8 + jj, pk.u);
      if (t == SS - 1) {
        f32x2 hv = {h2[0], h2[1]};
        *(f32x2*)(hlast + (p * MG + gm) * HH + k) = hv;
      }
    }

    // ---- signal: drain h stores to L3, then release own flag ----
    asm volatile("s_waitcnt vmcnt(0)" ::: "memory");
    __syncthreads();
    if (t < SS - 1 && tid == 0) {
      stg_dev4(gflags + q, (unsigned int)(t + 1));
    }
  }
}

__global__ void fc_kernel(const float* __restrict__ hlast, const float* __restrict__ W_fc,
                          const float* __restrict__ b_fc, float* __restrict__ out) {
  int b = blockIdx.x;            // 128
  int t = threadIdx.x;           // 256
  int o = t >> 2, part = t & 3;
  const float* hr = hlast + b * HH;
  const float* wr = W_fc + o * HH;
  float s = 0.f;
  #pragma unroll 4
  for (int k0 = part * 4; k0 < HH; k0 += 16) {
    float4 hv = *(const float4*)(hr + k0);
    float4 wv = *(const float4*)(wr + k0);
    s += hv.x * wv.x + hv.y * wv.y + hv.z * wv.z + hv.w * wv.w;
  }
  s += __shfl_xor(s, 1);
  s += __shfl_xor(s, 2);
  if (part == 0) out[b * OO + o] = s + b_fc[o];
}

extern "C" void kernel_launch(void* const* d_in, const int* in_sizes, int n_in,
                              void* d_out, int out_size, void* d_ws, size_t ws_size,
                              hipStream_t stream) {
  const float* x    = (const float*)d_in[0];
  const float* mask = (const float*)d_in[1];
  const float* ti   = (const float*)d_in[2];
  const float* W_ih = (const float*)d_in[3];
  const float* W_hh = (const float*)d_in[4];
  const float* b_ih = (const float*)d_in[5];
  const float* b_hh = (const float*)d_in[6];
  const float* W_fc = (const float*)d_in[7];
  const float* b_fc = (const float*)d_in[8];
  float* out = (float*)d_out;

  char* ws = (char*)d_ws;
  unsigned int* flags = (unsigned int*)ws;
  __bf16* hbuf  = (__bf16*)(ws + WS_HBUF);
  float*  hlast = (float*)(ws + WS_HLAST);
  __bf16* xtp   = (__bf16*)(ws + WS_XTP);
  __bf16* wihp  = (__bf16*)(ws + WS_WIHP);

  // zero flags + h double-buffers (ws poisoned 0xAA before each launch)
  hipMemsetAsync(ws, 0, WS_HLAST, stream);

  prepack_kernel<<<(SS * NGROUP * 2 * XTP_MT) / 256, 256, 0, stream>>>(x, mask, ti, xtp);
  wih_prepack<<<(GBLK * WIH_BLK) / 256, 256, 0, stream>>>(W_ih, wihp);
  lstm_scan<<<NGROUP * GBLK, 256, 0, stream>>>(W_hh, b_ih, b_hh, xtp, wihp, hbuf, hlast, flags);
  fc_kernel<<<BB, 256, 0, stream>>>(hlast, W_fc, b_fc, out);
}

// Round 8
// 2172.903 us; speedup vs baseline: 1.6472x; 1.0334x over previous
//
#include <hip/hip_runtime.h>
#include <hip/hip_bf16.h>

typedef __bf16 bf16x8 __attribute__((ext_vector_type(8)));
typedef float f32x4 __attribute__((ext_vector_type(4)));
typedef unsigned int u32x4 __attribute__((ext_vector_type(4)));

#define BB   128
#define SS   512
#define DD   128
#define HH   1024
#define OO   64
#define IIN  257

// 8 batch groups (16 rows) x 64 blocks; block owns 16 h-cols (64 gate cols).
// 4 waves = 4 K-quarters, W_hh B-frags persistent in VGPRs. 2 blocks/CU from
// different groups hide each other's sync-chain latency.
#define NGROUP 8
#define GBLK   64
#define MG     16
#define KK_H   32     // 1024/32 ksteps
#define KK_X   9      // 288/32

#define XTP_TP    (KK_X*512)      // 4608 bf16 per (t,p)
#define HBUF_SLAB (KK_H*512)      // 16384 bf16 = 32 KB per (p,buf)
#define WIH_BLK   (4*KK_X*512)    // 18432 bf16 per q

// ws layout (bytes): flags 8K | hbuf 512K | hlast 512K | xtp 36M | wihp 2.25M
#define WS_HBUF  8192
#define WS_HLAST 532480
#define WS_XTP   1056768
#define WS_WIHP  38805504

// ---- device-scope (sc1) ops: bypass L1/L2, coherent at L3 (MALL). No
// buffer_wbl2/buffer_inv anywhere -> no cache-maintenance serialization.
__device__ __forceinline__ u32x4 ldg_dev16(const void* p) {
  u32x4 r;
  asm volatile("global_load_dwordx4 %0, %1, off sc1" : "=v"(r) : "v"(p));
  return r;
}
__device__ __forceinline__ void stg_dev4(void* p, unsigned int v) {
  asm volatile("global_store_dword %0, %1, off sc1" :: "v"(p), "v"(v));
}
__device__ __forceinline__ bf16x8 asbf(u32x4 v) {
  union { u32x4 u; bf16x8 h; } c; c.u = v; return c.h;
}

#define CLAIMW4(CNTSTR, A, O)                                        \
  asm volatile("s_waitcnt vmcnt(" CNTSTR ")"                         \
    : "+v"((A)[(O)]), "+v"((A)[(O)+1]), "+v"((A)[(O)+2]), "+v"((A)[(O)+3]))

// xtp A-frags (16x16x32 A: m=lane&15, k=kk*32+(lane>>4)*8+j):
// idx = ((t*8+p)*9 + kk)*512 + l*8 + j
__global__ void prepack_kernel(const float* __restrict__ x, const float* __restrict__ mask,
                               const float* __restrict__ ti, __bf16* __restrict__ xtp) {
  int idx = blockIdx.x * 256 + threadIdx.x;        // 18,874,368
  int j = idx & 7, l = (idx >> 3) & 63;
  int rest = idx >> 9;
  int kk = rest % 9;
  int rest2 = rest / 9;
  int p = rest2 & 7;
  int t = rest2 >> 3;
  int b = p * MG + (l & 15);
  int k = kk * 32 + ((l >> 4) << 3) + j;
  float v;
  if (k < 128)       v = x[(b * SS + t) * DD + k];
  else if (k < 256)  v = mask[(b * SS + t) * DD + (k - 128)];
  else if (k == 256) v = ti[b * SS + t];
  else               v = 0.f;
  xtp[idx] = (__bf16)v;
}

// W_ih B-frags per col-slice q: [q][nt][kk][lane][8], nt = gate
__global__ void wih_prepack(const float* __restrict__ W_ih, __bf16* __restrict__ wihp) {
  int idx = blockIdx.x * 256 + threadIdx.x;        // 1,179,648
  int j = idx & 7, l = (idx >> 3) & 63;
  int rest = idx >> 9;
  int kk = rest % 9;
  int rest2 = rest / 9;
  int nt = rest2 & 3, q = rest2 >> 2;
  int col = nt * HH + q * 16 + (l & 15);
  int k = kk * 32 + ((l >> 4) << 3) + j;
  wihp[idx] = (k < IIN) ? (__bf16)W_ih[col * IIN + k] : (__bf16)0.f;
}

__device__ __forceinline__ float sigmoid_f(float v) { return 1.f / (1.f + __expf(-v)); }
__device__ __forceinline__ float tanh_f(float v)    { return 1.f - 2.f / (__expf(2.f * v) + 1.f); }

__launch_bounds__(256, 2)
__global__ void lstm_scan(const float* __restrict__ W_hh,
                          const float* __restrict__ b_ih, const float* __restrict__ b_hh,
                          const __bf16* __restrict__ xtp, const __bf16* __restrict__ wihp,
                          __bf16* __restrict__ hbuf,
                          float* __restrict__ hlast, unsigned int* __restrict__ flags) {
  // conflict-free reduce buffer: slot(w,g,r,qh,n16) =
  //   (((w*4+g)*4+r)*4+qh)*32 + n16*2 + (qh&1)   -> bank = 2*n16+(qh&1), 2-way
  __shared__ float red_lds[8192];   // 32 KB

  const int tid = threadIdx.x;
  const int bid = blockIdx.x;
  // adjacent dispatch ids -> different groups is NOT what we want for the
  // co-residency heuristic: typical breadth-first fill pairs bid and bid+256
  // on one CU -> groups p and p^4 (different). Contiguous 64-block groups.
  const int p = bid >> 6;                      // batch group [0,8)
  const int q = bid & 63;                      // col slice within group
  const int j0 = q * 16;                       // owned h-cols [j0, j0+16)

  const int w = tid >> 6, l = tid & 63;        // wave = K-quarter
  const int n16 = l & 15, qh = l >> 4;
  unsigned int* gflags = flags + p * 256;      // 64 blocks x 4 wave-flags

  // ---- W_hh B-fragments persistent in VGPRs: [nt][i], kk = w*8+i ----
  bf16x8 breg[4][8];
  #pragma unroll
  for (int ntI = 0; ntI < 4; ++ntI) {
    const float* wrow = W_hh + (size_t)(ntI * HH + j0 + n16) * HH;
    #pragma unroll
    for (int i = 0; i < 8; ++i) {
      const float* src = wrow + (w * 8 + i) * 32 + qh * 8;
      bf16x8 bv;
      #pragma unroll
      for (int jj = 0; jj < 8; ++jj) bv[jj] = (__bf16)src[jj];
      breg[ntI][i] = bv;
    }
  }

  // gate-phase cell ownership: this thread owns (row = qh*4 + w, col = j0+n16)
  const int grow = qh * 4 + w;
  float bias_r[4];
  #pragma unroll
  for (int g = 0; g < 4; ++g)
    bias_r[g] = b_ih[g * HH + j0 + n16] + b_hh[g * HH + j0 + n16];
  float creg = 0.f;

  // x-part K split over waves: kk in [xs, xe)
  const int xs = (w == 0) ? 0 : (2 * w + 1);
  const int xe = xs + ((w == 0) ? 3 : 2);

  for (int t = 0; t < SS; ++t) {
    const int rb = t & 1, wb = rb ^ 1;
    f32x4 acc[4];
    #pragma unroll
    for (int ntI = 0; ntI < 4; ++ntI) acc[ntI] = (f32x4){0.f, 0.f, 0.f, 0.f};

    // x-part (this wave's K-slice), pre-poll; A from xtp, B from wihp (cached)
    for (int kk = xs; kk < xe; ++kk) {
      const __bf16* xb = xtp + ((size_t)(t * 8 + p) * KK_X + kk) * 512 + l * 8;
      bf16x8 a = *(const bf16x8*)xb;
      #pragma unroll
      for (int ntI = 0; ntI < 4; ++ntI) {
        bf16x8 b = *(const bf16x8*)(wihp + ((size_t)(q * 4 + ntI) * KK_X + kk) * 512 + l * 8);
        acc[ntI] = __builtin_amdgcn_mfma_f32_16x16x32_bf16(a, b, acc[ntI], 0, 0, 0);
      }
    }

    // ---- barrier wait: all 64 blocks x 4 waves published h_t (sc1 polls) ----
    if (t > 0) {
      if (tid < 64) {
        const unsigned int tgt = (unsigned int)t;
        for (;;) {
          u32x4 f4;
          asm volatile("global_load_dwordx4 %0, %1, off sc1\n\t"
                       "s_waitcnt vmcnt(0)"
                       : "=v"(f4) : "v"(gflags + tid * 4));
          if (!__ballot(f4[0] < tgt || f4[1] < tgt || f4[2] < tgt || f4[3] < tgt)) break;
          __builtin_amdgcn_s_sleep(1);
        }
      }
      __syncthreads();
    }

    // h-part: this wave's K-quarter (8 ksteps). A via sc1 from L3, B from VGPRs.
    {
      const __bf16* hbL = hbuf + (p * 2 + rb) * HBUF_SLAB + (w * 8) * 512 + l * 8;
      u32x4 A[8];
      #pragma unroll
      for (int i = 0; i < 8; ++i) A[i] = ldg_dev16(hbL + i * 512);

      CLAIMW4("4", A, 0);
      #pragma unroll
      for (int i = 0; i < 4; ++i)
        #pragma unroll
        for (int ntI = 0; ntI < 4; ++ntI)
          acc[ntI] = __builtin_amdgcn_mfma_f32_16x16x32_bf16(asbf(A[i]), breg[ntI][i], acc[ntI], 0, 0, 0);
      CLAIMW4("0", A, 4);
      #pragma unroll
      for (int i = 4; i < 8; ++i)
        #pragma unroll
        for (int ntI = 0; ntI < 4; ++ntI)
          acc[ntI] = __builtin_amdgcn_mfma_f32_16x16x32_bf16(asbf(A[i]), breg[ntI][i], acc[ntI], 0, 0, 0);
    }

    // ---- deposit K-partials (conflict-free banking) ----
    #pragma unroll
    for (int g = 0; g < 4; ++g)
      #pragma unroll
      for (int r = 0; r < 4; ++r)
        red_lds[(((w * 4 + g) * 4 + r) * 4 + qh) * 32 + n16 * 2 + (qh & 1)] = acc[g][r];
    __syncthreads();

    // ---- gate phase: own cell (grow, j0+n16); own partial from register ----
    {
      __bf16* hw = hbuf + (p * 2 + wb) * HBUF_SLAB;
      float gv[4];
      #pragma unroll
      for (int g = 0; g < 4; ++g) {
        // own wave's partial for r = w (wave-uniform select)
        float own = (w == 0) ? acc[g][0] : (w == 1) ? acc[g][1]
                  : (w == 2) ? acc[g][2] : acc[g][3];
        float s = own + bias_r[g];
        #pragma unroll
        for (int wo = 0; wo < 4; ++wo)
          if (wo != w)   // w wave-uniform: 3 reads survive per wave
            s += red_lds[(((wo * 4 + g) * 4 + w) * 4 + qh) * 32 + n16 * 2 + (qh & 1)];
        gv[g] = s;
      }
      // NOTE: wo loop with runtime w: compiler resolves via uniform branches.
      float i_ = sigmoid_f(gv[0]);
      float f_ = sigmoid_f(gv[1]);
      float g_ = tanh_f(gv[2]);
      float o_ = sigmoid_f(gv[3]);
      float c  = f_ * creg + i_ * g_;
      creg = c;
      float h  = o_ * tanh_f(c);

      // pack 2 adjacent cols via shfl, even lanes store one dword
      union { __bf16 b; unsigned short u; } cv; cv.b = (__bf16)h;
      unsigned int hu = (unsigned int)cv.u;
      unsigned int partner = __shfl_xor(hu, 1);
      if ((n16 & 1) == 0) {
        unsigned int dw = hu | (partner << 16);
        int k = j0 + n16;
        int kk = k >> 5, q2 = (k >> 3) & 3, jj = k & 7;
        stg_dev4(hw + kk * 512 + (q2 * 16 + grow) * 8 + jj, dw);
      }
      if (t == SS - 1) hlast[(p * MG + grow) * HH + j0 + n16] = h;
    }

    // ---- per-wave signal: drain own wave's stores, lane0 releases wave-flag ----
    asm volatile("s_waitcnt vmcnt(0)" ::: "memory");
    if (t < SS - 1 && l == 0) {
      stg_dev4(gflags + q * 4 + w, (unsigned int)(t + 1));
    }
  }
}

__global__ void fc_kernel(const float* __restrict__ hlast, const float* __restrict__ W_fc,
                          const float* __restrict__ b_fc, float* __restrict__ out) {
  int b = blockIdx.x;            // 128
  int t = threadIdx.x;           // 256
  int o = t >> 2, part = t & 3;
  const float* hr = hlast + b * HH;
  const float* wr = W_fc + o * HH;
  float s = 0.f;
  #pragma unroll 4
  for (int k0 = part * 4; k0 < HH; k0 += 16) {
    float4 hv = *(const float4*)(hr + k0);
    float4 wv = *(const float4*)(wr + k0);
    s += hv.x * wv.x + hv.y * wv.y + hv.z * wv.z + hv.w * wv.w;
  }
  s += __shfl_xor(s, 1);
  s += __shfl_xor(s, 2);
  if (part == 0) out[b * OO + o] = s + b_fc[o];
}

extern "C" void kernel_launch(void* const* d_in, const int* in_sizes, int n_in,
                              void* d_out, int out_size, void* d_ws, size_t ws_size,
                              hipStream_t stream) {
  const float* x    = (const float*)d_in[0];
  const float* mask = (const float*)d_in[1];
  const float* ti   = (const float*)d_in[2];
  const float* W_ih = (const float*)d_in[3];
  const float* W_hh = (const float*)d_in[4];
  const float* b_ih = (const float*)d_in[5];
  const float* b_hh = (const float*)d_in[6];
  const float* W_fc = (const float*)d_in[7];
  const float* b_fc = (const float*)d_in[8];
  float* out = (float*)d_out;

  char* ws = (char*)d_ws;
  unsigned int* flags = (unsigned int*)ws;
  __bf16* hbuf  = (__bf16*)(ws + WS_HBUF);
  float*  hlast = (float*)(ws + WS_HLAST);
  __bf16* xtp   = (__bf16*)(ws + WS_XTP);
  __bf16* wihp  = (__bf16*)(ws + WS_WIHP);

  // zero flags + h double-buffers (ws poisoned 0xAA before each launch)
  hipMemsetAsync(ws, 0, WS_HLAST, stream);

  prepack_kernel<<<(SS * NGROUP * XTP_TP) / 256, 256, 0, stream>>>(x, mask, ti, xtp);
  wih_prepack<<<(GBLK * WIH_BLK) / 256, 256, 0, stream>>>(W_ih, wihp);
  lstm_scan<<<NGROUP * GBLK, 256, 0, stream>>>(W_hh, b_ih, b_hh, xtp, wihp, hbuf, hlast, flags);
  fc_kernel<<<BB, 256, 0, stream>>>(hlast, W_fc, b_fc, out);
}